// Round 7
// baseline (239.618 us; speedup 1.0000x reference)
//
#include <hip/hip_runtime.h>
#include <hip/hip_bf16.h>

// B=2, T=2048, DM=1024, H=16, DK=DV=64
// ws layout (56 MB):
//   [0,2)MB  Wqt bf16 [n=h*64+k][d]   [2,4) Wkt   [4,6) Wvt   [6,8) Wot [n=DM][k=H*DV]
//   [8,32)   Xb bf16 [3][4096][1024]  (xq,xk,xv cast)  -- dead after proj
//   [8,16)   AO bf16 [t][h*64+dv]     (ALIASES Xq slot; written by attn)
//   [32,40)  Qb bf16 [b][h][t][dk]
//   [40,48)  Kt2 bf16 [bh][64 ktile][s:1][dc:1][c:16][q4:4][j:8]  (K A-frag tiled)
//   [48,56)  Vt2 bf16 [bh][64 ktile][64 dv][32 k']  (V^T tiled, key-permuted sigma)

typedef __attribute__((ext_vector_type(8))) short short8;
typedef __attribute__((ext_vector_type(4))) short short4v;
typedef __attribute__((ext_vector_type(4))) float f32x4;
typedef __attribute__((ext_vector_type(4))) int i32x4;

__device__ __forceinline__ short f2bf(float f) {
  union { float f; unsigned u; } v; v.f = f;
  unsigned r = v.u + 0x7FFFu + ((v.u >> 16) & 1u);  // RNE
  return (short)(r >> 16);
}

#define GLD_LDS(g, l) __builtin_amdgcn_global_load_lds( \
    (const __attribute__((address_space(1))) void*)(g), \
    (__attribute__((address_space(3))) void*)(l), 16, 0, 0)

// ---------------- fused prep: x cast | Wq/k/v transpose | Wo transpose -----
__global__ __launch_bounds__(256) void prep_all(
    const float* __restrict__ xq, const float* __restrict__ xk,
    const float* __restrict__ xv, const float* __restrict__ wq,
    const float* __restrict__ wk, const float* __restrict__ wv,
    const float* __restrict__ wo,
    short* __restrict__ Xb, short* __restrict__ Wall, short* __restrict__ Wot)
{
  const int bx = blockIdx.x, tid = threadIdx.x;
  __shared__ float Lt[64][65];
  if (bx < 6144) {                       // ---- x cast (2048 blocks per z)
    int z = bx >> 11;
    const float* x = z == 0 ? xq : (z == 1 ? xk : xv);
    size_t i = ((size_t)(bx & 2047) * 256 + tid) * 8;
    f32x4 f0 = *(const f32x4*)(x + i);
    f32x4 f1 = *(const f32x4*)(x + i + 4);
    short8 s;
#pragma unroll
    for (int j = 0; j < 4; j++) { s[j] = f2bf(f0[j]); s[4 + j] = f2bf(f1[j]); }
    *(short8*)(Xb + (size_t)z * 4194304 + i) = s;
  } else if (bx < 6912) {                // ---- Wq/k/v transpose (256 per z)
    int bz = bx - 6144;
    int z = bz >> 8, inner = bz & 255;
    const float* w = z == 0 ? wq : (z == 1 ? wk : wv);
    short* Wt = Wall + (size_t)z * 1048576;
    int h = inner >> 4, d0 = (inner & 15) * 64;
#pragma unroll
    for (int it = 0; it < 4; it++) {
      int e = tid + it * 256;
      int dl = e >> 4, k4 = (e & 15) * 4;
      f32x4 v = *(const f32x4*)(w + ((size_t)(h * 1024 + d0 + dl) * 64) + k4);
#pragma unroll
      for (int j = 0; j < 4; j++) Lt[dl][k4 + j] = v[j];
    }
    __syncthreads();
#pragma unroll
    for (int it = 0; it < 4; it++) {
      int e = tid + it * 256;
      int kl = e >> 4, dq = e & 15;
      short4v s;
#pragma unroll
      for (int j = 0; j < 4; j++) s[j] = f2bf(Lt[dq * 4 + j][kl]);
      *(short4v*)(Wt + (size_t)(h * 64 + kl) * 1024 + d0 + dq * 4) = s;
    }
  } else {                               // ---- Wo transpose (256 blocks)
    int bz = bx - 6912;
    int k0 = (bz >> 4) * 64, n0 = (bz & 15) * 64;
#pragma unroll
    for (int it = 0; it < 4; it++) {
      int e = tid + it * 256;
      int kl = e >> 4, n4 = (e & 15) * 4;
      f32x4 v = *(const f32x4*)(wo + (size_t)(k0 + kl) * 1024 + n0 + n4);
#pragma unroll
      for (int j = 0; j < 4; j++) Lt[kl][n4 + j] = v[j];
    }
    __syncthreads();
#pragma unroll
    for (int it = 0; it < 4; it++) {
      int e = tid + it * 256;
      int nl = e >> 4, kq = e & 15;
      short4v s;
#pragma unroll
      for (int j = 0; j < 4; j++) s[j] = f2bf(Lt[kq * 4 + j][nl]);
      *(short4v*)(Wot + (size_t)(n0 + nl) * 1024 + k0 + kq * 4) = s;
    }
  }
}

// ---------------- QKV projection: m97-style 128x128 LDS-staged GEMM --------
// R3-exact (benched clean in R4): z==1 writes A-frag-tiled Kt2 (vectorized
// short4 store, NO mask folding); z==2 writes key-permuted Vt2.
__global__ __launch_bounds__(256) void proj_qkv2(
    const short* __restrict__ Xb, const short* __restrict__ Wall,
    short* __restrict__ Qb, short* __restrict__ Kt2, short* __restrict__ Vt2)
{
  const int z = blockIdx.z;
  const short* X  = Xb   + (size_t)z * 4194304;
  const short* Wt = Wall + (size_t)z * 1048576;

  const int t0 = blockIdx.x * 128;   // 32
  const int n0 = blockIdx.y * 128;   // 8
  const int tid = threadIdx.x, w = tid >> 6, lane = tid & 63;
  const int c = lane & 15, q4 = lane >> 4;
  const int wn = (w & 1) * 64, wt = (w >> 1) * 64;
  const int srow = lane >> 2, scol = (lane & 3) * 8;

  __shared__ __align__(16) short Al[128 * 32];
  __shared__ __align__(16) short Bl[128 * 32];

  f32x4 acc[4][4] = {};

  for (int k0 = 0; k0 < 1024; k0 += 32) {
#pragma unroll
    for (int i = 0; i < 2; i++) {
      int rg = (w * 2 + i) * 16;
      GLD_LDS(Wt + (size_t)(n0 + rg + srow) * 1024 + k0 + scol, Al + rg * 32);
      GLD_LDS(X  + (size_t)(t0 + rg + srow) * 1024 + k0 + scol, Bl + rg * 32);
    }
    __syncthreads();
    short8 a[4], bfr[4];
#pragma unroll
    for (int i = 0; i < 4; i++)
      a[i] = *(const short8*)(Al + (wn + i * 16 + c) * 32 + q4 * 8);
#pragma unroll
    for (int j = 0; j < 4; j++)
      bfr[j] = *(const short8*)(Bl + (wt + j * 16 + c) * 32 + q4 * 8);
#pragma unroll
    for (int i = 0; i < 4; i++)
#pragma unroll
      for (int j = 0; j < 4; j++)
        acc[i][j] = __builtin_amdgcn_mfma_f32_16x16x32_bf16(a[i], bfr[j], acc[i][j], 0, 0, 0);
    __syncthreads();
  }

#pragma unroll
  for (int i = 0; i < 4; i++)
#pragma unroll
    for (int j = 0; j < 4; j++) {
      int n = n0 + wn + i * 16 + q4 * 4;       // h*64 + d base (+4 consecutive)
      int trow = t0 + wt + j * 16 + c;
      int b = trow >> 11, t = trow & 2047;
      int h = n >> 6, cc = n & 63;
      int bh = b * 16 + h;
      f32x4 v = acc[i][j];
      short4v pk;
#pragma unroll
      for (int r = 0; r < 4; r++) pk[r] = f2bf(v[r]);
      if (z == 0) {
        *(short4v*)(Qb + (size_t)(bh * 2048 + t) * 64 + cc) = pk;
      } else if (z == 1) {
        // Kt2 tile: offset ((s*2+dc)*16 + c_)*32 + q4_*8 + j ; cc%4==0 ->
        // the 4 d-values share chunk bits -> one short4 store
        int t5 = t & 31, s_ = t5 >> 4, c_ = t5 & 15;
        size_t base = (size_t)bh * 131072 + (t >> 5) * 2048;
        size_t off = base + ((s_ * 2 + (cc >> 5)) * 16 + c_) * 32 +
                     ((cc >> 3) & 3) * 8 + (cc & 7);
        *(short4v*)(Kt2 + off) = pk;
      } else {
        int t5 = t & 31;   // sigma: [s:1][g:2][m:1][b:1] -> [g:2][s:1][m:1][b:1]
        int kp = ((t5 >> 2) & 3) * 8 + ((t5 >> 4) & 1) * 4 + (t5 & 3);
        size_t base = (size_t)bh * 131072 + (t >> 5) * 2048;
#pragma unroll
        for (int r = 0; r < 4; r++)
          Vt2[base + (size_t)(cc + r) * 32 + kp] = pk[r];
      }
    }
}

// ---------------- fused attention v12: attn8 skeleton + 64 q-rows/wave -----
// BISECT round: attn8 (R3-benched PASS, 62.5us) verbatim -- 4 waves/block,
// wave stages 2 segments (2 GLD/tile), 3 LDS buffers, counted vmcnt(2),
// Ml-based per-tile cm/cb, perm packing -- with ONLY the 64-row extension:
// qa/st/acc/l u-extent 2->4, qrow0 = tblk*256 + w*64, grid.y 16->8.
// Tests the R4 LDS-BW theory: per-CU DS demand/slot drops 8x12 -> 4x10 b128
// while each K/V fragment feeds 4 MFMAs instead of 2.
__global__ __launch_bounds__(256, 1) void attn12(
    const short* __restrict__ Qb, const short* __restrict__ Kt2,
    const short* __restrict__ Vt2, const float* __restrict__ mask,
    short* __restrict__ AO)
{
  const int bh = blockIdx.x;
  const int tblk = blockIdx.y;
  const int b = bh >> 4, h = bh & 15;
  const short* Qh = Qb  + (size_t)bh * 131072;
  const short* Kh = Kt2 + (size_t)bh * 131072;
  const short* Vh = Vt2 + (size_t)bh * 131072;

  const int tid = threadIdx.x, w = tid >> 6, lane = tid & 63;
  const int c = lane & 15, q4 = lane >> 4;
  const int qrow0 = tblk * 256 + w * 64;        // 4 waves x 64 rows = 256/block

  // LDS: 3 x [seg 0..3 = K frags | seg 4..7 = V frags], 512 shorts/seg = 24KB
  __shared__ __align__(16) short KV[3][4096];
  __shared__ __align__(16) float Ml[2048];      // mask row for this batch, 8KB

  // ds_read offset swizzle (involution, matches pre-swizzled global source)
  const int ch = c * 4 + q4;
  const int rdo = (ch ^ ((ch >> 3) & 3)) * 8;
  const int sch = (lane ^ ((lane >> 3) & 3)) * 8;

  // mask -> LDS (one-time; drained before the pipeline starts)
  {
    f32x4 m0 = *(const f32x4*)(mask + b * 2048 + tid * 8);
    f32x4 m1 = *(const f32x4*)(mask + b * 2048 + tid * 8 + 4);
    *(f32x4*)(&Ml[tid * 8]) = m0;
    *(f32x4*)(&Ml[tid * 8 + 4]) = m1;
  }

  // Q fragments for the whole loop (B-operand: n=qrow=c, k=q4*8+j)
  short8 qa[4][2];
#pragma unroll
  for (int u = 0; u < 4; u++)
#pragma unroll
    for (int dc = 0; dc < 2; dc++)
      qa[u][dc] = *(const short8*)(Qh + (size_t)(qrow0 + u * 16 + c) * 64 + dc * 32 + q4 * 8);

  f32x4 acc[4][4] = {};
  float l[4] = {0.f, 0.f, 0.f, 0.f};
  const float LOG2E_64 = 1.44269504088896f * 0.015625f;

  // wave w stages segments {2w, 2w+1}: g<4 -> K frag g, g>=4 -> V frag g-4
  const int g0 = w * 2;

#define STAGE(BI, T) do { \
    const short* sb = (g0 < 4) ? (Kh + (size_t)(T) * 2048 + g0 * 512) \
                               : (Vh + (size_t)(T) * 2048 + (g0 - 4) * 512); \
    GLD_LDS(sb + sch,        &KV[BI][g0 * 512]); \
    GLD_LDS(sb + 512 + sch,  &KV[BI][g0 * 512 + 512]); \
  } while (0)

#define BODY(BI, TT) do { \
    const short* Kb = &KV[BI][0]; \
    short8 kf[2][2], va[4]; \
    _Pragma("unroll") \
    for (int s = 0; s < 2; s++) \
      _Pragma("unroll") \
      for (int dc = 0; dc < 2; dc++) \
        kf[s][dc] = *(const short8*)(Kb + (s * 2 + dc) * 512 + rdo); \
    _Pragma("unroll") \
    for (int vs = 0; vs < 4; vs++) \
      va[vs] = *(const short8*)(Kb + (4 + vs) * 512 + rdo); \
    f32x4 st[4][2] = {}; \
    _Pragma("unroll") \
    for (int u = 0; u < 4; u++) \
      _Pragma("unroll") \
      for (int s = 0; s < 2; s++) { \
        st[u][s] = __builtin_amdgcn_mfma_f32_16x16x32_bf16(kf[s][0], qa[u][0], st[u][s], 0, 0, 0); \
        st[u][s] = __builtin_amdgcn_mfma_f32_16x16x32_bf16(kf[s][1], qa[u][1], st[u][s], 0, 0, 0); \
      } \
    f32x4 cm[2], cb[2]; \
    _Pragma("unroll") \
    for (int s = 0; s < 2; s++) { \
      f32x4 mk = *(const f32x4*)(&Ml[(TT) * 32 + q4 * 4 + s * 16]); \
      cm[s] = mk * LOG2E_64; \
      cb[s] = (mk - 1.0f) * 240.0f; \
    } \
    _Pragma("unroll") \
    for (int u = 0; u < 4; u++) { \
      unsigned pkd[2][2]; \
      _Pragma("unroll") \
      for (int s = 0; s < 2; s++) { \
        float e0 = __builtin_amdgcn_exp2f(st[u][s][0] * cm[s][0] + cb[s][0]); \
        float e1 = __builtin_amdgcn_exp2f(st[u][s][1] * cm[s][1] + cb[s][1]); \
        float e2 = __builtin_amdgcn_exp2f(st[u][s][2] * cm[s][2] + cb[s][2]); \
        float e3 = __builtin_amdgcn_exp2f(st[u][s][3] * cm[s][3] + cb[s][3]); \
        l[u] += (e0 + e1) + (e2 + e3); \
        union { float f; unsigned u; } a0, a1, a2, a3; \
        a0.f = e0; a1.f = e1; a2.f = e2; a3.f = e3; \
        pkd[s][0] = __builtin_amdgcn_perm(a1.u + 0x8000u, a0.u + 0x8000u, 0x07060302u); \
        pkd[s][1] = __builtin_amdgcn_perm(a3.u + 0x8000u, a2.u + 0x8000u, 0x07060302u); \
      } \
      union { i32x4 i; short8 s; } pb; \
      pb.i[0] = (int)pkd[0][0]; pb.i[1] = (int)pkd[0][1]; \
      pb.i[2] = (int)pkd[1][0]; pb.i[3] = (int)pkd[1][1]; \
      _Pragma("unroll") \
      for (int vs = 0; vs < 4; vs++) \
        acc[u][vs] = __builtin_amdgcn_mfma_f32_16x16x32_bf16(va[vs], pb.s, acc[u][vs], 0, 0, 0); \
    } \
  } while (0)

  __syncthreads();                                  // mask visible; full drain
  asm volatile("s_waitcnt vmcnt(0)" ::: "memory");  // clean vmcnt baseline
  __builtin_amdgcn_sched_barrier(0);
  STAGE(0, 0);
  STAGE(1, 1);                                      // 4 loads in flight

  int bi = 0;
  for (int t = 0; t < 62; ++t) {
    asm volatile("s_waitcnt vmcnt(2)" ::: "memory");  // own tile-t loads done
    __builtin_amdgcn_sched_barrier(0);
    __builtin_amdgcn_s_barrier();                     // everyone's tile-t done
    __builtin_amdgcn_sched_barrier(0);
    int si = bi + 2; if (si >= 3) si -= 3;
    STAGE(si, t + 2);                                 // refill; back to 4 in flight
    BODY(bi, t);
    bi = (bi + 1 == 3) ? 0 : bi + 1;
  }
  asm volatile("s_waitcnt vmcnt(2)" ::: "memory");
  __builtin_amdgcn_sched_barrier(0);
  __builtin_amdgcn_s_barrier();
  __builtin_amdgcn_sched_barrier(0);
  BODY(bi, 62);                                      // bi == 2
  asm volatile("s_waitcnt vmcnt(0)" ::: "memory");
  __builtin_amdgcn_sched_barrier(0);
  __builtin_amdgcn_s_barrier();
  __builtin_amdgcn_sched_barrier(0);
  BODY(0, 63);
#undef STAGE
#undef BODY

  // epilogue: l reduce across q4 groups, normalize, store
#pragma unroll
  for (int u = 0; u < 4; u++) {
    float lu = l[u];
    lu += __shfl_xor(lu, 16);
    lu += __shfl_xor(lu, 32);
    float inv = 1.0f / lu;
    size_t row = (size_t)b * 2048 + qrow0 + u * 16 + c;
#pragma unroll
    for (int vs = 0; vs < 4; vs++) {
      f32x4 v = acc[u][vs];
      short4v pk;
#pragma unroll
      for (int r = 0; r < 4; r++) pk[r] = f2bf(v[r] * inv);
      *(short4v*)(AO + row * 1024 + h * 64 + vs * 16 + q4 * 4) = pk;
    }
  }
}

// ---------------- output projection: m97 GEMM, fp32+bias epilogue ----------
__global__ __launch_bounds__(256) void out_proj2(
    const short* __restrict__ AO, const short* __restrict__ Wot,
    const float* __restrict__ bo, float* __restrict__ out)
{
  const int t0 = blockIdx.x * 128;   // 32
  const int n0 = blockIdx.y * 128;   // 8
  const int tid = threadIdx.x, w = tid >> 6, lane = tid & 63;
  const int c = lane & 15, q4 = lane >> 4;
  const int wn = (w & 1) * 64, wt = (w >> 1) * 64;
  const int srow = lane >> 2, scol = (lane & 3) * 8;

  __shared__ __align__(16) short Al[128 * 32];
  __shared__ __align__(16) short Bl[128 * 32];

  f32x4 acc[4][4] = {};

  for (int k0 = 0; k0 < 1024; k0 += 32) {
#pragma unroll
    for (int i = 0; i < 2; i++) {
      int rg = (w * 2 + i) * 16;
      GLD_LDS(Wot + (size_t)(n0 + rg + srow) * 1024 + k0 + scol, Al + rg * 32);
      GLD_LDS(AO  + (size_t)(t0 + rg + srow) * 1024 + k0 + scol, Bl + rg * 32);
    }
    __syncthreads();
    short8 a[4], bfr[4];
#pragma unroll
    for (int i = 0; i < 4; i++)
      a[i] = *(const short8*)(Al + (wn + i * 16 + c) * 32 + q4 * 8);
#pragma unroll
    for (int j = 0; j < 4; j++)
      bfr[j] = *(const short8*)(Bl + (wt + j * 16 + c) * 32 + q4 * 8);
#pragma unroll
    for (int i = 0; i < 4; i++)
#pragma unroll
      for (int j = 0; j < 4; j++)
        acc[i][j] = __builtin_amdgcn_mfma_f32_16x16x32_bf16(a[i], bfr[j], acc[i][j], 0, 0, 0);
    __syncthreads();
  }

#pragma unroll
  for (int i = 0; i < 4; i++)
#pragma unroll
    for (int j = 0; j < 4; j++) {
      int n = n0 + wn + i * 16 + q4 * 4;
      int trow = t0 + wt + j * 16 + c;
      f32x4 v = acc[i][j] + *(const f32x4*)(bo + n);
      *(f32x4*)(out + (size_t)trow * 1024 + n) = v;
    }
}

extern "C" void kernel_launch(void* const* d_in, const int* in_sizes, int n_in,
                              void* d_out, int out_size, void* d_ws, size_t ws_size,
                              hipStream_t stream)
{
  (void)in_sizes; (void)n_in; (void)out_size; (void)ws_size;
  const float* xq   = (const float*)d_in[0];
  const float* xk   = (const float*)d_in[1];
  const float* xv   = (const float*)d_in[2];
  const float* mask = (const float*)d_in[3];
  const float* wq   = (const float*)d_in[4];
  const float* wk   = (const float*)d_in[5];
  const float* wv   = (const float*)d_in[6];
  const float* wo   = (const float*)d_in[7];
  const float* bo   = (const float*)d_in[8];
  float* out = (float*)d_out;

  char* ws = (char*)d_ws;                    // needs 56 MB
  short* Wall = (short*)(ws + (size_t)0);    // Wq/Wk/Wv contiguous
  short* Wot  = (short*)(ws + ((size_t)6 << 20));
  short* Xb   = (short*)(ws + ((size_t)8 << 20));   // 24 MB, dead after proj
  short* AO   = (short*)(ws + ((size_t)8 << 20));   // aliases Xq slot (8 MB)
  short* Qb   = (short*)(ws + ((size_t)32 << 20));
  short* Kt2  = (short*)(ws + ((size_t)40 << 20));  // K A-frag pre-tiled
  short* Vt2  = (short*)(ws + ((size_t)48 << 20));  // V^T pre-tiled, key-permuted

  prep_all<<<7168, 256, 0, stream>>>(xq, xk, xv, wq, wk, wv, wo, Xb, Wall, Wot);
  proj_qkv2<<<dim3(32, 8, 3), 256, 0, stream>>>(Xb, Wall, Qb, Kt2, Vt2);
  attn12<<<dim3(32, 8), 256, 0, stream>>>(Qb, Kt2, Vt2, mask, AO);
  out_proj2<<<dim3(32, 8), 256, 0, stream>>>(AO, Wot, bo, out);
}

// Round 8
// 227.740 us; speedup vs baseline: 1.0522x; 1.0522x over previous
//
#include <hip/hip_runtime.h>
#include <hip/hip_bf16.h>

// B=2, T=2048, DM=1024, H=16, DK=DV=64
// ws layout (56 MB):
//   [0,2)MB  Wqt bf16 [n=h*64+k][d]   [2,4) Wkt   [4,6) Wvt   [6,8) Wot [n=DM][k=H*DV]
//   [8,32)   Xb bf16 [3][4096][1024]  (xq,xk,xv cast)  -- dead after proj
//   [8,16)   AO bf16 [t][h*64+dv]     (ALIASES Xq slot; written by attn)
//   [32,40)  Qb bf16 [b][h][t][dk]
//   [40,48)  Kt2 bf16 [bh][64 ktile][s:1][dc:1][c:16][q4:4][j:8]  (K A-frag tiled)
//   [48,56)  Vt2 bf16 [bh][64 ktile][64 dv][32 k']  (V^T tiled, key-permuted sigma)

typedef __attribute__((ext_vector_type(8))) short short8;
typedef __attribute__((ext_vector_type(4))) short short4v;
typedef __attribute__((ext_vector_type(4))) float f32x4;
typedef __attribute__((ext_vector_type(4))) int i32x4;

__device__ __forceinline__ short f2bf(float f) {
  union { float f; unsigned u; } v; v.f = f;
  unsigned r = v.u + 0x7FFFu + ((v.u >> 16) & 1u);  // RNE
  return (short)(r >> 16);
}

#define GLD_LDS(g, l) __builtin_amdgcn_global_load_lds( \
    (const __attribute__((address_space(1))) void*)(g), \
    (__attribute__((address_space(3))) void*)(l), 16, 0, 0)

// ---------------- fused prep: x cast | Wq/k/v transpose | Wo transpose -----
__global__ __launch_bounds__(256) void prep_all(
    const float* __restrict__ xq, const float* __restrict__ xk,
    const float* __restrict__ xv, const float* __restrict__ wq,
    const float* __restrict__ wk, const float* __restrict__ wv,
    const float* __restrict__ wo,
    short* __restrict__ Xb, short* __restrict__ Wall, short* __restrict__ Wot)
{
  const int bx = blockIdx.x, tid = threadIdx.x;
  __shared__ float Lt[64][65];
  if (bx < 6144) {                       // ---- x cast (2048 blocks per z)
    int z = bx >> 11;
    const float* x = z == 0 ? xq : (z == 1 ? xk : xv);
    size_t i = ((size_t)(bx & 2047) * 256 + tid) * 8;
    f32x4 f0 = *(const f32x4*)(x + i);
    f32x4 f1 = *(const f32x4*)(x + i + 4);
    short8 s;
#pragma unroll
    for (int j = 0; j < 4; j++) { s[j] = f2bf(f0[j]); s[4 + j] = f2bf(f1[j]); }
    *(short8*)(Xb + (size_t)z * 4194304 + i) = s;
  } else if (bx < 6912) {                // ---- Wq/k/v transpose (256 per z)
    int bz = bx - 6144;
    int z = bz >> 8, inner = bz & 255;
    const float* w = z == 0 ? wq : (z == 1 ? wk : wv);
    short* Wt = Wall + (size_t)z * 1048576;
    int h = inner >> 4, d0 = (inner & 15) * 64;
#pragma unroll
    for (int it = 0; it < 4; it++) {
      int e = tid + it * 256;
      int dl = e >> 4, k4 = (e & 15) * 4;
      f32x4 v = *(const f32x4*)(w + ((size_t)(h * 1024 + d0 + dl) * 64) + k4);
#pragma unroll
      for (int j = 0; j < 4; j++) Lt[dl][k4 + j] = v[j];
    }
    __syncthreads();
#pragma unroll
    for (int it = 0; it < 4; it++) {
      int e = tid + it * 256;
      int kl = e >> 4, dq = e & 15;
      short4v s;
#pragma unroll
      for (int j = 0; j < 4; j++) s[j] = f2bf(Lt[dq * 4 + j][kl]);
      *(short4v*)(Wt + (size_t)(h * 64 + kl) * 1024 + d0 + dq * 4) = s;
    }
  } else {                               // ---- Wo transpose (256 blocks)
    int bz = bx - 6912;
    int k0 = (bz >> 4) * 64, n0 = (bz & 15) * 64;
#pragma unroll
    for (int it = 0; it < 4; it++) {
      int e = tid + it * 256;
      int kl = e >> 4, n4 = (e & 15) * 4;
      f32x4 v = *(const f32x4*)(wo + (size_t)(k0 + kl) * 1024 + n0 + n4);
#pragma unroll
      for (int j = 0; j < 4; j++) Lt[kl][n4 + j] = v[j];
    }
    __syncthreads();
#pragma unroll
    for (int it = 0; it < 4; it++) {
      int e = tid + it * 256;
      int nl = e >> 4, kq = e & 15;
      short4v s;
#pragma unroll
      for (int j = 0; j < 4; j++) s[j] = f2bf(Lt[kq * 4 + j][nl]);
      *(short4v*)(Wot + (size_t)(n0 + nl) * 1024 + k0 + kq * 4) = s;
    }
  }
}

// ---------------- QKV projection: m97-style 128x128 LDS-staged GEMM --------
// R3/R7-exact (benched clean): z==1 writes A-frag-tiled Kt2 (vectorized
// short4 store); z==2 writes key-permuted Vt2.
__global__ __launch_bounds__(256) void proj_qkv2(
    const short* __restrict__ Xb, const short* __restrict__ Wall,
    short* __restrict__ Qb, short* __restrict__ Kt2, short* __restrict__ Vt2)
{
  const int z = blockIdx.z;
  const short* X  = Xb   + (size_t)z * 4194304;
  const short* Wt = Wall + (size_t)z * 1048576;

  const int t0 = blockIdx.x * 128;   // 32
  const int n0 = blockIdx.y * 128;   // 8
  const int tid = threadIdx.x, w = tid >> 6, lane = tid & 63;
  const int c = lane & 15, q4 = lane >> 4;
  const int wn = (w & 1) * 64, wt = (w >> 1) * 64;
  const int srow = lane >> 2, scol = (lane & 3) * 8;

  __shared__ __align__(16) short Al[128 * 32];
  __shared__ __align__(16) short Bl[128 * 32];

  f32x4 acc[4][4] = {};

  for (int k0 = 0; k0 < 1024; k0 += 32) {
#pragma unroll
    for (int i = 0; i < 2; i++) {
      int rg = (w * 2 + i) * 16;
      GLD_LDS(Wt + (size_t)(n0 + rg + srow) * 1024 + k0 + scol, Al + rg * 32);
      GLD_LDS(X  + (size_t)(t0 + rg + srow) * 1024 + k0 + scol, Bl + rg * 32);
    }
    __syncthreads();
    short8 a[4], bfr[4];
#pragma unroll
    for (int i = 0; i < 4; i++)
      a[i] = *(const short8*)(Al + (wn + i * 16 + c) * 32 + q4 * 8);
#pragma unroll
    for (int j = 0; j < 4; j++)
      bfr[j] = *(const short8*)(Bl + (wt + j * 16 + c) * 32 + q4 * 8);
#pragma unroll
    for (int i = 0; i < 4; i++)
#pragma unroll
      for (int j = 0; j < 4; j++)
        acc[i][j] = __builtin_amdgcn_mfma_f32_16x16x32_bf16(a[i], bfr[j], acc[i][j], 0, 0, 0);
    __syncthreads();
  }

#pragma unroll
  for (int i = 0; i < 4; i++)
#pragma unroll
    for (int j = 0; j < 4; j++) {
      int n = n0 + wn + i * 16 + q4 * 4;       // h*64 + d base (+4 consecutive)
      int trow = t0 + wt + j * 16 + c;
      int b = trow >> 11, t = trow & 2047;
      int h = n >> 6, cc = n & 63;
      int bh = b * 16 + h;
      f32x4 v = acc[i][j];
      short4v pk;
#pragma unroll
      for (int r = 0; r < 4; r++) pk[r] = f2bf(v[r]);
      if (z == 0) {
        *(short4v*)(Qb + (size_t)(bh * 2048 + t) * 64 + cc) = pk;
      } else if (z == 1) {
        // Kt2 tile: offset ((s*2+dc)*16 + c_)*32 + q4_*8 + j ; cc%4==0 ->
        // the 4 d-values share chunk bits -> one short4 store
        int t5 = t & 31, s_ = t5 >> 4, c_ = t5 & 15;
        size_t base = (size_t)bh * 131072 + (t >> 5) * 2048;
        size_t off = base + ((s_ * 2 + (cc >> 5)) * 16 + c_) * 32 +
                     ((cc >> 3) & 3) * 8 + (cc & 7);
        *(short4v*)(Kt2 + off) = pk;
      } else {
        int t5 = t & 31;   // sigma: [s:1][g:2][m:1][b:1] -> [g:2][s:1][m:1][b:1]
        int kp = ((t5 >> 2) & 3) * 8 + ((t5 >> 4) & 1) * 4 + (t5 & 3);
        size_t base = (size_t)bh * 131072 + (t >> 5) * 2048;
#pragma unroll
        for (int r = 0; r < 4; r++)
          Vt2[base + (size_t)(cc + r) * 32 + kp] = pk[r];
      }
    }
}

// ---------------- fused attention v13: K via LDS, V via global regs --------
// attn9 skeleton (R4-benched PASS, 58us: 4 waves x 32 rows, QK(t+1)||SMPV(t),
// counted vmcnt) with the V path moved OFF the LDS port: R7 established the
// 2-block/CU configs sit at ~88% LDS-port occupancy (8 waves x 10 b128 x
// ~12cyc ~ the whole 1088-cyc tile slot). v13 splits the two streams:
//  - K stays LDS-staged (1 GLD_LDS per wave per tile, 3 buffers, ahead-2)
//  - V loads straight from L2-resident Vt2 (R0-proven access pattern) into
//    ping-pong register sets vaA/vaB, prefetched 1 tile ahead (T14).
// Per-CU per tile: DS 8x6 b128 ~ 576 cyc, L2 32KB ~ 570 cyc -- two ports in
// parallel instead of 960 cyc stacked on LDS. vmcnt per wave per half:
// S(stage)=1 op, P(V-prefetch)=4 ops; steady-state wait vmcnt(5) retires
// exactly {S(t+1), P(t)}. V-reg deps are also compiler-tracked (safety net).
__global__ __launch_bounds__(256, 2) void attn13(
    const short* __restrict__ Qb, const short* __restrict__ Kt2,
    const short* __restrict__ Vt2, const float* __restrict__ mask,
    short* __restrict__ AO)
{
  const int bh = blockIdx.x;
  const int tblk = blockIdx.y;
  const int b = bh >> 4, h = bh & 15;
  const short* Qh = Qb  + (size_t)bh * 131072;
  const short* Kh = Kt2 + (size_t)bh * 131072;
  const short* Vh = Vt2 + (size_t)bh * 131072;

  const int tid = threadIdx.x, w = tid >> 6, lane = tid & 63;
  const int c = lane & 15, q4 = lane >> 4;
  const int qrow0 = tblk * 128 + w * 32;

  __shared__ __align__(16) short Kl[3][2048];   // 12KB: 3 K buffers (4 segs)
  __shared__ __align__(16) float cmL[2048];     // mask * log2e/64
  __shared__ __align__(16) float cbL[2048];     // (mask-1) * 240

  const int ch = c * 4 + q4;
  const int rdo = (ch ^ ((ch >> 3) & 3)) * 8;   // swizzled ds_read offset
  const int sch = (lane ^ ((lane >> 3) & 3)) * 8;
  const int vch = c * 32 + q4 * 8;              // V global frag offset (R0)

  // mask coefficient precompute (8 elems/thread)
  {
    const float LOG2E_64c = 1.44269504088896f * 0.015625f;
    f32x4 m0 = *(const f32x4*)(mask + b * 2048 + tid * 8);
    f32x4 m1 = *(const f32x4*)(mask + b * 2048 + tid * 8 + 4);
    *(f32x4*)(&cmL[tid * 8])     = m0 * LOG2E_64c;
    *(f32x4*)(&cmL[tid * 8 + 4]) = m1 * LOG2E_64c;
    *(f32x4*)(&cbL[tid * 8])     = (m0 - 1.0f) * 240.0f;
    *(f32x4*)(&cbL[tid * 8 + 4]) = (m1 - 1.0f) * 240.0f;
  }

  // Q fragments for the whole loop (B-operand: n=qrow=c, k=q4*8+j)
  short8 qa[2][2];
#pragma unroll
  for (int u = 0; u < 2; u++)
#pragma unroll
    for (int dc = 0; dc < 2; dc++)
      qa[u][dc] = *(const short8*)(Qh + (size_t)(qrow0 + u * 16 + c) * 64 + dc * 32 + q4 * 8);

  f32x4 acc[2][4] = {};
  float l[2] = {0.f, 0.f};

  // wave w stages K seg w (ONE global_load_lds per tile per wave)
#define STAGE(BI, T) \
    GLD_LDS(Kh + (size_t)(T) * 2048 + w * 512 + sch, &Kl[BI][w * 512])

  // V fragment prefetch for tile T1 straight from global into regs
#define PREFV(VA, T1) do { \
    const short* vb = Vh + (size_t)(T1) * 2048 + vch; \
    VA[0] = *(const short8*)(vb); \
    VA[1] = *(const short8*)(vb + 512); \
    VA[2] = *(const short8*)(vb + 1024); \
    VA[3] = *(const short8*)(vb + 1536); \
  } while (0)

  // QK phase: ds_read K frags from buffer BI, 8 QK MFMAs -> ST
#define QK(BI, ST) do { \
    const short* Kb = &Kl[BI][0]; \
    short8 kf[2][2]; \
    _Pragma("unroll") \
    for (int s = 0; s < 2; s++) \
      _Pragma("unroll") \
      for (int dc = 0; dc < 2; dc++) \
        kf[s][dc] = *(const short8*)(Kb + (s * 2 + dc) * 512 + rdo); \
    _Pragma("unroll") \
    for (int u = 0; u < 2; u++) \
      _Pragma("unroll") \
      for (int s = 0; s < 2; s++) { \
        f32x4 z = {}; \
        z = __builtin_amdgcn_mfma_f32_16x16x32_bf16(kf[s][0], qa[u][0], z, 0, 0, 0); \
        ST[u][s] = __builtin_amdgcn_mfma_f32_16x16x32_bf16(kf[s][1], qa[u][1], z, 0, 0, 0); \
      } \
  } while (0)

  // SMPV phase: softmax on ST (tile TT) + 8 PV MFMAs with reg-resident VA
#define SMPV(ST, VA, TT) do { \
    f32x4 cm[2], cb[2]; \
    _Pragma("unroll") \
    for (int s = 0; s < 2; s++) { \
      cm[s] = *(const f32x4*)(&cmL[(TT) * 32 + q4 * 4 + s * 16]); \
      cb[s] = *(const f32x4*)(&cbL[(TT) * 32 + q4 * 4 + s * 16]); \
    } \
    _Pragma("unroll") \
    for (int u = 0; u < 2; u++) { \
      unsigned pkd[2][2]; \
      _Pragma("unroll") \
      for (int s = 0; s < 2; s++) { \
        float e0 = __builtin_amdgcn_exp2f(ST[u][s][0] * cm[s][0] + cb[s][0]); \
        float e1 = __builtin_amdgcn_exp2f(ST[u][s][1] * cm[s][1] + cb[s][1]); \
        float e2 = __builtin_amdgcn_exp2f(ST[u][s][2] * cm[s][2] + cb[s][2]); \
        float e3 = __builtin_amdgcn_exp2f(ST[u][s][3] * cm[s][3] + cb[s][3]); \
        l[u] += (e0 + e1) + (e2 + e3); \
        unsigned p01, p23; \
        asm("v_cvt_pk_bf16_f32 %0, %1, %2" : "=v"(p01) : "v"(e0), "v"(e1)); \
        asm("v_cvt_pk_bf16_f32 %0, %1, %2" : "=v"(p23) : "v"(e2), "v"(e3)); \
        pkd[s][0] = p01; pkd[s][1] = p23; \
      } \
      union { i32x4 i; short8 s; } pb; \
      pb.i[0] = (int)pkd[0][0]; pb.i[1] = (int)pkd[0][1]; \
      pb.i[2] = (int)pkd[1][0]; pb.i[3] = (int)pkd[1][1]; \
      _Pragma("unroll") \
      for (int vs = 0; vs < 4; vs++) \
        acc[u][vs] = __builtin_amdgcn_mfma_f32_16x16x32_bf16(VA[vs], pb.s, acc[u][vs], 0, 0, 0); \
    } \
  } while (0)

#define WAITVL(N) do { \
    asm volatile("s_waitcnt vmcnt(" #N ") lgkmcnt(0)" ::: "memory"); \
    __builtin_amdgcn_sched_barrier(0); } while (0)
#define SBAR() do { __builtin_amdgcn_s_barrier(); \
    __builtin_amdgcn_sched_barrier(0); } while (0)

  f32x4 stA[2][2], stB[2][2];
  short8 vaA[4], vaB[4];

  // ---- prologue ----
  __syncthreads();                                  // cmL/cbL visible
  asm volatile("s_waitcnt vmcnt(0)" ::: "memory");  // clean vmcnt baseline
  __builtin_amdgcn_sched_barrier(0);
  STAGE(0, 0);
  STAGE(1, 1);
  PREFV(vaA, 0);                                    // in flight: S0,S1,P0 = 6
  WAITVL(5);                                        // S0 done
  SBAR();                                           // K(0) visible everywhere
  STAGE(2, 2);
  QK(0, stA);                                       // tile 0
  PREFV(vaB, 1);                                    // in flight: S1,P0,S2,P1

  // ---- main loop: t = 0,2,...,58 ----
  int bs = 0;                                       // == t % 3 at half-A top
  for (int ii = 0; ii < 30; ++ii) {
    const int t = 2 * ii;
    int b1 = bs + 1; if (b1 == 3) b1 = 0;
    int b2 = b1 + 1; if (b2 == 3) b2 = 0;
    // half A: QK(t+1) || SMPV(t)
    WAITVL(5);                       // retires S(t+1), P(t)
    SBAR();                          // K(t+1) visible; buffer bs free
    STAGE(bs, t + 3);
    QK(b1, stB);
    SMPV(stA, vaA, t);
    PREFV(vaA, t + 2);
    // half B: QK(t+2) || SMPV(t+1)
    WAITVL(5);                       // retires S(t+2), P(t+1)
    SBAR();
    STAGE(b1, t + 4);
    QK(b2, stA);
    SMPV(stB, vaB, t + 1);
    PREFV(vaB, t + 3);
    bs = b2;
  }
  // ---- tail: t = 60..63 (bs == 0 here; in flight S61,P60,S62,P61) ----
  WAITVL(5);                         // retires S(61), P(60)
  SBAR();
  STAGE(0, 63);                      // 63 % 3 == 0
  QK(1, stB);                        // tile 61
  SMPV(stA, vaA, 60);
  PREFV(vaA, 62);
  WAITVL(5);                         // retires S(62), P(61)
  SBAR();
  QK(2, stA);                        // tile 62
  SMPV(stB, vaB, 61);
  PREFV(vaB, 63);
  WAITVL(4);                         // retires S(63), P(62); P(63) outstanding
  SBAR();
  QK(0, stB);                        // tile 63
  SMPV(stA, vaA, 62);
  WAITVL(0);                         // P(63) done
  SMPV(stB, vaB, 63);
#undef STAGE
#undef PREFV
#undef QK
#undef SMPV
#undef WAITVL
#undef SBAR

  // epilogue: l reduce across q4 groups, normalize, store
#pragma unroll
  for (int u = 0; u < 2; u++) {
    float lu = l[u];
    lu += __shfl_xor(lu, 16);
    lu += __shfl_xor(lu, 32);
    float inv = 1.0f / lu;
    size_t row = (size_t)b * 2048 + qrow0 + u * 16 + c;
#pragma unroll
    for (int vs = 0; vs < 4; vs++) {
      f32x4 v = acc[u][vs];
      short4v pk;
#pragma unroll
      for (int r = 0; r < 4; r++) pk[r] = f2bf(v[r] * inv);
      *(short4v*)(AO + row * 1024 + h * 64 + vs * 16 + q4 * 4) = pk;
    }
  }
}

// ---------------- output projection: m97 GEMM, fp32+bias epilogue ----------
__global__ __launch_bounds__(256) void out_proj2(
    const short* __restrict__ AO, const short* __restrict__ Wot,
    const float* __restrict__ bo, float* __restrict__ out)
{
  const int t0 = blockIdx.x * 128;   // 32
  const int n0 = blockIdx.y * 128;   // 8
  const int tid = threadIdx.x, w = tid >> 6, lane = tid & 63;
  const int c = lane & 15, q4 = lane >> 4;
  const int wn = (w & 1) * 64, wt = (w >> 1) * 64;
  const int srow = lane >> 2, scol = (lane & 3) * 8;

  __shared__ __align__(16) short Al[128 * 32];
  __shared__ __align__(16) short Bl[128 * 32];

  f32x4 acc[4][4] = {};

  for (int k0 = 0; k0 < 1024; k0 += 32) {
#pragma unroll
    for (int i = 0; i < 2; i++) {
      int rg = (w * 2 + i) * 16;
      GLD_LDS(Wot + (size_t)(n0 + rg + srow) * 1024 + k0 + scol, Al + rg * 32);
      GLD_LDS(AO  + (size_t)(t0 + rg + srow) * 1024 + k0 + scol, Bl + rg * 32);
    }
    __syncthreads();
    short8 a[4], bfr[4];
#pragma unroll
    for (int i = 0; i < 4; i++)
      a[i] = *(const short8*)(Al + (wn + i * 16 + c) * 32 + q4 * 8);
#pragma unroll
    for (int j = 0; j < 4; j++)
      bfr[j] = *(const short8*)(Bl + (wt + j * 16 + c) * 32 + q4 * 8);
#pragma unroll
    for (int i = 0; i < 4; i++)
#pragma unroll
      for (int j = 0; j < 4; j++)
        acc[i][j] = __builtin_amdgcn_mfma_f32_16x16x32_bf16(a[i], bfr[j], acc[i][j], 0, 0, 0);
    __syncthreads();
  }

#pragma unroll
  for (int i = 0; i < 4; i++)
#pragma unroll
    for (int j = 0; j < 4; j++) {
      int n = n0 + wn + i * 16 + q4 * 4;
      int trow = t0 + wt + j * 16 + c;
      f32x4 v = acc[i][j] + *(const f32x4*)(bo + n);
      *(f32x4*)(out + (size_t)trow * 1024 + n) = v;
    }
}

extern "C" void kernel_launch(void* const* d_in, const int* in_sizes, int n_in,
                              void* d_out, int out_size, void* d_ws, size_t ws_size,
                              hipStream_t stream)
{
  (void)in_sizes; (void)n_in; (void)out_size; (void)ws_size;
  const float* xq   = (const float*)d_in[0];
  const float* xk   = (const float*)d_in[1];
  const float* xv   = (const float*)d_in[2];
  const float* mask = (const float*)d_in[3];
  const float* wq   = (const float*)d_in[4];
  const float* wk   = (const float*)d_in[5];
  const float* wv   = (const float*)d_in[6];
  const float* wo   = (const float*)d_in[7];
  const float* bo   = (const float*)d_in[8];
  float* out = (float*)d_out;

  char* ws = (char*)d_ws;                    // needs 56 MB
  short* Wall = (short*)(ws + (size_t)0);    // Wq/Wk/Wv contiguous
  short* Wot  = (short*)(ws + ((size_t)6 << 20));
  short* Xb   = (short*)(ws + ((size_t)8 << 20));   // 24 MB, dead after proj
  short* AO   = (short*)(ws + ((size_t)8 << 20));   // aliases Xq slot (8 MB)
  short* Qb   = (short*)(ws + ((size_t)32 << 20));
  short* Kt2  = (short*)(ws + ((size_t)40 << 20));  // K A-frag pre-tiled
  short* Vt2  = (short*)(ws + ((size_t)48 << 20));  // V^T pre-tiled, key-permuted

  prep_all<<<7168, 256, 0, stream>>>(xq, xk, xv, wq, wk, wv, wo, Xb, Wall, Wot);
  proj_qkv2<<<dim3(32, 8, 3), 256, 0, stream>>>(Xb, Wall, Qb, Kt2, Vt2);
  attn13<<<dim3(32, 16), 256, 0, stream>>>(Qb, Kt2, Vt2, mask, AO);
  out_proj2<<<dim3(32, 8), 256, 0, stream>>>(AO, Wot, bo, out);
}

// Round 9
// 220.407 us; speedup vs baseline: 1.0872x; 1.0333x over previous
//
#include <hip/hip_runtime.h>
#include <hip/hip_bf16.h>

// B=2, T=2048, DM=1024, H=16, DK=DV=64
// ws layout (56 MB):
//   [0,2)MB  Wqt bf16 [n=h*64+k][d]   [2,4) Wkt   [4,6) Wvt   [6,8) Wot [n=DM][k=H*DV]
//   [8,32)   Xb bf16 [3][4096][1024]  (xq,xk,xv cast)  -- dead after proj
//   [8,16)   AO bf16 [t][h*64+dv]     (ALIASES Xq slot; written by attn)
//   [32,40)  Qb bf16 [b][h][t][dk]
//   [40,48)  Kt2 bf16 [bh][64 ktile][s:1][dc:1][c:16][q4:4][j:8]  (K A-frag tiled)
//   [48,56)  Vt2 bf16 [bh][64 ktile][64 dv][32 k']  (V^T tiled, key-permuted sigma)

typedef __attribute__((ext_vector_type(8))) short short8;
typedef __attribute__((ext_vector_type(4))) short short4v;
typedef __attribute__((ext_vector_type(4))) float f32x4;
typedef __attribute__((ext_vector_type(4))) int i32x4;

__device__ __forceinline__ short f2bf(float f) {
  union { float f; unsigned u; } v; v.f = f;
  unsigned r = v.u + 0x7FFFu + ((v.u >> 16) & 1u);  // RNE
  return (short)(r >> 16);
}

#define GLD_LDS(g, l) __builtin_amdgcn_global_load_lds( \
    (const __attribute__((address_space(1))) void*)(g), \
    (__attribute__((address_space(3))) void*)(l), 16, 0, 0)

// ---------------- fused prep: x cast | Wq/k/v transpose | Wo transpose -----
__global__ __launch_bounds__(256) void prep_all(
    const float* __restrict__ xq, const float* __restrict__ xk,
    const float* __restrict__ xv, const float* __restrict__ wq,
    const float* __restrict__ wk, const float* __restrict__ wv,
    const float* __restrict__ wo,
    short* __restrict__ Xb, short* __restrict__ Wall, short* __restrict__ Wot)
{
  const int bx = blockIdx.x, tid = threadIdx.x;
  __shared__ float Lt[64][65];
  if (bx < 6144) {                       // ---- x cast (2048 blocks per z)
    int z = bx >> 11;
    const float* x = z == 0 ? xq : (z == 1 ? xk : xv);
    size_t i = ((size_t)(bx & 2047) * 256 + tid) * 8;
    f32x4 f0 = *(const f32x4*)(x + i);
    f32x4 f1 = *(const f32x4*)(x + i + 4);
    short8 s;
#pragma unroll
    for (int j = 0; j < 4; j++) { s[j] = f2bf(f0[j]); s[4 + j] = f2bf(f1[j]); }
    *(short8*)(Xb + (size_t)z * 4194304 + i) = s;
  } else if (bx < 6912) {                // ---- Wq/k/v transpose (256 per z)
    int bz = bx - 6144;
    int z = bz >> 8, inner = bz & 255;
    const float* w = z == 0 ? wq : (z == 1 ? wk : wv);
    short* Wt = Wall + (size_t)z * 1048576;
    int h = inner >> 4, d0 = (inner & 15) * 64;
#pragma unroll
    for (int it = 0; it < 4; it++) {
      int e = tid + it * 256;
      int dl = e >> 4, k4 = (e & 15) * 4;
      f32x4 v = *(const f32x4*)(w + ((size_t)(h * 1024 + d0 + dl) * 64) + k4);
#pragma unroll
      for (int j = 0; j < 4; j++) Lt[dl][k4 + j] = v[j];
    }
    __syncthreads();
#pragma unroll
    for (int it = 0; it < 4; it++) {
      int e = tid + it * 256;
      int kl = e >> 4, dq = e & 15;
      short4v s;
#pragma unroll
      for (int j = 0; j < 4; j++) s[j] = f2bf(Lt[dq * 4 + j][kl]);
      *(short4v*)(Wt + (size_t)(h * 64 + kl) * 1024 + d0 + dq * 4) = s;
    }
  } else {                               // ---- Wo transpose (256 blocks)
    int bz = bx - 6912;
    int k0 = (bz >> 4) * 64, n0 = (bz & 15) * 64;
#pragma unroll
    for (int it = 0; it < 4; it++) {
      int e = tid + it * 256;
      int kl = e >> 4, n4 = (e & 15) * 4;
      f32x4 v = *(const f32x4*)(wo + (size_t)(k0 + kl) * 1024 + n0 + n4);
#pragma unroll
      for (int j = 0; j < 4; j++) Lt[kl][n4 + j] = v[j];
    }
    __syncthreads();
#pragma unroll
    for (int it = 0; it < 4; it++) {
      int e = tid + it * 256;
      int nl = e >> 4, kq = e & 15;
      short4v s;
#pragma unroll
      for (int j = 0; j < 4; j++) s[j] = f2bf(Lt[kq * 4 + j][nl]);
      *(short4v*)(Wot + (size_t)(n0 + nl) * 1024 + k0 + kq * 4) = s;
    }
  }
}

// ---------------- QKV projection: m97-style 128x128 LDS-staged GEMM --------
// R3/R7-exact (benched clean): z==1 writes A-frag-tiled Kt2 (vectorized
// short4 store); z==2 writes key-permuted Vt2.
__global__ __launch_bounds__(256) void proj_qkv2(
    const short* __restrict__ Xb, const short* __restrict__ Wall,
    short* __restrict__ Qb, short* __restrict__ Kt2, short* __restrict__ Vt2)
{
  const int z = blockIdx.z;
  const short* X  = Xb   + (size_t)z * 4194304;
  const short* Wt = Wall + (size_t)z * 1048576;

  const int t0 = blockIdx.x * 128;   // 32
  const int n0 = blockIdx.y * 128;   // 8
  const int tid = threadIdx.x, w = tid >> 6, lane = tid & 63;
  const int c = lane & 15, q4 = lane >> 4;
  const int wn = (w & 1) * 64, wt = (w >> 1) * 64;
  const int srow = lane >> 2, scol = (lane & 3) * 8;

  __shared__ __align__(16) short Al[128 * 32];
  __shared__ __align__(16) short Bl[128 * 32];

  f32x4 acc[4][4] = {};

  for (int k0 = 0; k0 < 1024; k0 += 32) {
#pragma unroll
    for (int i = 0; i < 2; i++) {
      int rg = (w * 2 + i) * 16;
      GLD_LDS(Wt + (size_t)(n0 + rg + srow) * 1024 + k0 + scol, Al + rg * 32);
      GLD_LDS(X  + (size_t)(t0 + rg + srow) * 1024 + k0 + scol, Bl + rg * 32);
    }
    __syncthreads();
    short8 a[4], bfr[4];
#pragma unroll
    for (int i = 0; i < 4; i++)
      a[i] = *(const short8*)(Al + (wn + i * 16 + c) * 32 + q4 * 8);
#pragma unroll
    for (int j = 0; j < 4; j++)
      bfr[j] = *(const short8*)(Bl + (wt + j * 16 + c) * 32 + q4 * 8);
#pragma unroll
    for (int i = 0; i < 4; i++)
#pragma unroll
      for (int j = 0; j < 4; j++)
        acc[i][j] = __builtin_amdgcn_mfma_f32_16x16x32_bf16(a[i], bfr[j], acc[i][j], 0, 0, 0);
    __syncthreads();
  }

#pragma unroll
  for (int i = 0; i < 4; i++)
#pragma unroll
    for (int j = 0; j < 4; j++) {
      int n = n0 + wn + i * 16 + q4 * 4;       // h*64 + d base (+4 consecutive)
      int trow = t0 + wt + j * 16 + c;
      int b = trow >> 11, t = trow & 2047;
      int h = n >> 6, cc = n & 63;
      int bh = b * 16 + h;
      f32x4 v = acc[i][j];
      short4v pk;
#pragma unroll
      for (int r = 0; r < 4; r++) pk[r] = f2bf(v[r]);
      if (z == 0) {
        *(short4v*)(Qb + (size_t)(bh * 2048 + t) * 64 + cc) = pk;
      } else if (z == 1) {
        // Kt2 tile: offset ((s*2+dc)*16 + c_)*32 + q4_*8 + j ; cc%4==0 ->
        // the 4 d-values share chunk bits -> one short4 store
        int t5 = t & 31, s_ = t5 >> 4, c_ = t5 & 15;
        size_t base = (size_t)bh * 131072 + (t >> 5) * 2048;
        size_t off = base + ((s_ * 2 + (cc >> 5)) * 16 + c_) * 32 +
                     ((cc >> 3) & 3) * 8 + (cc & 7);
        *(short4v*)(Kt2 + off) = pk;
      } else {
        int t5 = t & 31;   // sigma: [s:1][g:2][m:1][b:1] -> [g:2][s:1][m:1][b:1]
        int kp = ((t5 >> 2) & 3) * 8 + ((t5 >> 4) & 1) * 4 + (t5 & 3);
        size_t base = (size_t)bh * 131072 + (t >> 5) * 2048;
#pragma unroll
        for (int r = 0; r < 4; r++)
          Vt2[base + (size_t)(cc + r) * 32 + kp] = pk[r];
      }
    }
}

// ---------------- fused attention v14: 2 K-tiles per barrier phase ---------
// R8 falsified the LDS-port theory (V off LDS: no change). Across R1-R8 the
// per-tile slot is ~1100 cyc invariant to occupancy, HBM, VALU count, and DS
// traffic -- the residual is the per-tile waitcnt+barrier rendezvous itself.
// v14 amortizes it: each phase stages and computes TWO tiles (4 GLD/wave,
// 16 ds_read, 32 MFMA, 2 softmaxes) with ONE vmcnt(0)+__syncthreads -- half
// the barriers of attn9, plus free cross-tile ILP inside the unrolled body
// (QK of tile 2p+1 is independent of SM/PV of tile 2p). Sync = v7-proven
// full-drain double-buffer (no counted vmcnt -> spill-immune). K+V layout,
// cmL/cbL tables, cvt_pk softmax, XCD-swizzled grid all kept from attn9.
__global__ __launch_bounds__(256, 2) void attn14(
    const short* __restrict__ Qb, const short* __restrict__ Kt2,
    const short* __restrict__ Vt2, const float* __restrict__ mask,
    short* __restrict__ AO)
{
  const int bh = blockIdx.x;
  const int tblk = blockIdx.y;
  const int b = bh >> 4, h = bh & 15;
  const short* Qh = Qb  + (size_t)bh * 131072;
  const short* Kh = Kt2 + (size_t)bh * 131072;
  const short* Vh = Vt2 + (size_t)bh * 131072;

  const int tid = threadIdx.x, w = tid >> 6, lane = tid & 63;
  const int c = lane & 15, q4 = lane >> 4;
  const int qrow0 = tblk * 128 + w * 32;

  // LDS: 2 phase-buffers x 2 tiles x [K segs 0..3 | V segs 4..7] = 32 KB
  __shared__ __align__(16) short KV2[2][8192];
  __shared__ __align__(16) float cmL[2048];     // mask * log2e/64
  __shared__ __align__(16) float cbL[2048];     // (mask-1) * 240

  const int ch = c * 4 + q4;
  const int rdo = (ch ^ ((ch >> 3) & 3)) * 8;   // swizzled ds_read offset
  const int sch = (lane ^ ((lane >> 3) & 3)) * 8;

  // mask coefficient precompute (8 elems/thread)
  {
    const float LOG2E_64c = 1.44269504088896f * 0.015625f;
    f32x4 m0 = *(const f32x4*)(mask + b * 2048 + tid * 8);
    f32x4 m1 = *(const f32x4*)(mask + b * 2048 + tid * 8 + 4);
    *(f32x4*)(&cmL[tid * 8])     = m0 * LOG2E_64c;
    *(f32x4*)(&cmL[tid * 8 + 4]) = m1 * LOG2E_64c;
    *(f32x4*)(&cbL[tid * 8])     = (m0 - 1.0f) * 240.0f;
    *(f32x4*)(&cbL[tid * 8 + 4]) = (m1 - 1.0f) * 240.0f;
  }

  // Q fragments for the whole loop (B-operand: n=qrow=c, k=q4*8+j)
  short8 qa[2][2];
#pragma unroll
  for (int u = 0; u < 2; u++)
#pragma unroll
    for (int dc = 0; dc < 2; dc++)
      qa[u][dc] = *(const short8*)(Qh + (size_t)(qrow0 + u * 16 + c) * 64 + dc * 32 + q4 * 8);

  f32x4 acc[2][4] = {};
  float l[2] = {0.f, 0.f};

  // wave w stages segments {2w, 2w+1} of BOTH tiles of a phase:
  // g<4 -> K frag g at tile-offset 0..2047, g>=4 -> V frag g-4 at 2048..4095
  const int g0 = w * 2;

#define STAGE(BI, P) do { \
    const short* s0 = (g0 < 4) ? (Kh + (size_t)(2 * (P)) * 2048 + g0 * 512) \
                               : (Vh + (size_t)(2 * (P)) * 2048 + (g0 - 4) * 512); \
    GLD_LDS(s0 + sch,         &KV2[BI][g0 * 512]); \
    GLD_LDS(s0 + 512 + sch,   &KV2[BI][g0 * 512 + 512]); \
    const short* s1 = (g0 < 4) ? (Kh + (size_t)(2 * (P) + 1) * 2048 + g0 * 512) \
                               : (Vh + (size_t)(2 * (P) + 1) * 2048 + (g0 - 4) * 512); \
    GLD_LDS(s1 + sch,         &KV2[BI][4096 + g0 * 512]); \
    GLD_LDS(s1 + 512 + sch,   &KV2[BI][4096 + g0 * 512 + 512]); \
  } while (0)

  // one tile: ds_read K+V frags at LDS base KB, QK 8 MFMA, softmax, PV 8 MFMA
#define BODY1(KB, TT) do { \
    const short* Kb = (KB); \
    short8 kf[2][2], va[4]; \
    _Pragma("unroll") \
    for (int s = 0; s < 2; s++) \
      _Pragma("unroll") \
      for (int dc = 0; dc < 2; dc++) \
        kf[s][dc] = *(const short8*)(Kb + (s * 2 + dc) * 512 + rdo); \
    _Pragma("unroll") \
    for (int vs = 0; vs < 4; vs++) \
      va[vs] = *(const short8*)(Kb + 2048 + vs * 512 + rdo); \
    f32x4 st[2][2]; \
    _Pragma("unroll") \
    for (int u = 0; u < 2; u++) \
      _Pragma("unroll") \
      for (int s = 0; s < 2; s++) { \
        f32x4 z = {}; \
        z = __builtin_amdgcn_mfma_f32_16x16x32_bf16(kf[s][0], qa[u][0], z, 0, 0, 0); \
        st[u][s] = __builtin_amdgcn_mfma_f32_16x16x32_bf16(kf[s][1], qa[u][1], z, 0, 0, 0); \
      } \
    f32x4 cm[2], cb[2]; \
    _Pragma("unroll") \
    for (int s = 0; s < 2; s++) { \
      cm[s] = *(const f32x4*)(&cmL[(TT) * 32 + q4 * 4 + s * 16]); \
      cb[s] = *(const f32x4*)(&cbL[(TT) * 32 + q4 * 4 + s * 16]); \
    } \
    _Pragma("unroll") \
    for (int u = 0; u < 2; u++) { \
      unsigned pkd[2][2]; \
      _Pragma("unroll") \
      for (int s = 0; s < 2; s++) { \
        float e0 = __builtin_amdgcn_exp2f(st[u][s][0] * cm[s][0] + cb[s][0]); \
        float e1 = __builtin_amdgcn_exp2f(st[u][s][1] * cm[s][1] + cb[s][1]); \
        float e2 = __builtin_amdgcn_exp2f(st[u][s][2] * cm[s][2] + cb[s][2]); \
        float e3 = __builtin_amdgcn_exp2f(st[u][s][3] * cm[s][3] + cb[s][3]); \
        l[u] += (e0 + e1) + (e2 + e3); \
        unsigned p01, p23; \
        asm("v_cvt_pk_bf16_f32 %0, %1, %2" : "=v"(p01) : "v"(e0), "v"(e1)); \
        asm("v_cvt_pk_bf16_f32 %0, %1, %2" : "=v"(p23) : "v"(e2), "v"(e3)); \
        pkd[s][0] = p01; pkd[s][1] = p23; \
      } \
      union { i32x4 i; short8 s; } pb; \
      pb.i[0] = (int)pkd[0][0]; pb.i[1] = (int)pkd[0][1]; \
      pb.i[2] = (int)pkd[1][0]; pb.i[3] = (int)pkd[1][1]; \
      _Pragma("unroll") \
      for (int vs = 0; vs < 4; vs++) \
        acc[u][vs] = __builtin_amdgcn_mfma_f32_16x16x32_bf16(va[vs], pb.s, acc[u][vs], 0, 0, 0); \
    } \
  } while (0)

#define BODY(BI, P) do { \
    BODY1(&KV2[BI][0],    2 * (P)); \
    BODY1(&KV2[BI][4096], 2 * (P) + 1); \
  } while (0)

  __syncthreads();                                  // cmL/cbL visible
  asm volatile("s_waitcnt vmcnt(0)" ::: "memory");  // qa/mask loads drained
  STAGE(0, 0);
  asm volatile("s_waitcnt vmcnt(0)" ::: "memory");  // phase 0 landed
  __syncthreads();
  int cur = 0;
  for (int p = 0; p < 31; ++p) {
    STAGE(cur ^ 1, p + 1);          // stage next phase while computing current
    BODY(cur, p);
    asm volatile("s_waitcnt vmcnt(0)" ::: "memory");
    __syncthreads();                // staged data visible; readers done
    cur ^= 1;
  }
  BODY(cur, 31);
#undef STAGE
#undef BODY1
#undef BODY

  // epilogue: l reduce across q4 groups, normalize, store
#pragma unroll
  for (int u = 0; u < 2; u++) {
    float lu = l[u];
    lu += __shfl_xor(lu, 16);
    lu += __shfl_xor(lu, 32);
    float inv = 1.0f / lu;
    size_t row = (size_t)b * 2048 + qrow0 + u * 16 + c;
#pragma unroll
    for (int vs = 0; vs < 4; vs++) {
      f32x4 v = acc[u][vs];
      short4v pk;
#pragma unroll
      for (int r = 0; r < 4; r++) pk[r] = f2bf(v[r] * inv);
      *(short4v*)(AO + row * 1024 + h * 64 + vs * 16 + q4 * 4) = pk;
    }
  }
}

// ---------------- output projection: m97 GEMM, fp32+bias epilogue ----------
__global__ __launch_bounds__(256) void out_proj2(
    const short* __restrict__ AO, const short* __restrict__ Wot,
    const float* __restrict__ bo, float* __restrict__ out)
{
  const int t0 = blockIdx.x * 128;   // 32
  const int n0 = blockIdx.y * 128;   // 8
  const int tid = threadIdx.x, w = tid >> 6, lane = tid & 63;
  const int c = lane & 15, q4 = lane >> 4;
  const int wn = (w & 1) * 64, wt = (w >> 1) * 64;
  const int srow = lane >> 2, scol = (lane & 3) * 8;

  __shared__ __align__(16) short Al[128 * 32];
  __shared__ __align__(16) short Bl[128 * 32];

  f32x4 acc[4][4] = {};

  for (int k0 = 0; k0 < 1024; k0 += 32) {
#pragma unroll
    for (int i = 0; i < 2; i++) {
      int rg = (w * 2 + i) * 16;
      GLD_LDS(Wot + (size_t)(n0 + rg + srow) * 1024 + k0 + scol, Al + rg * 32);
      GLD_LDS(AO  + (size_t)(t0 + rg + srow) * 1024 + k0 + scol, Bl + rg * 32);
    }
    __syncthreads();
    short8 a[4], bfr[4];
#pragma unroll
    for (int i = 0; i < 4; i++)
      a[i] = *(const short8*)(Al + (wn + i * 16 + c) * 32 + q4 * 8);
#pragma unroll
    for (int j = 0; j < 4; j++)
      bfr[j] = *(const short8*)(Bl + (wt + j * 16 + c) * 32 + q4 * 8);
#pragma unroll
    for (int i = 0; i < 4; i++)
#pragma unroll
      for (int j = 0; j < 4; j++)
        acc[i][j] = __builtin_amdgcn_mfma_f32_16x16x32_bf16(a[i], bfr[j], acc[i][j], 0, 0, 0);
    __syncthreads();
  }

#pragma unroll
  for (int i = 0; i < 4; i++)
#pragma unroll
    for (int j = 0; j < 4; j++) {
      int n = n0 + wn + i * 16 + q4 * 4;
      int trow = t0 + wt + j * 16 + c;
      f32x4 v = acc[i][j] + *(const f32x4*)(bo + n);
      *(f32x4*)(out + (size_t)trow * 1024 + n) = v;
    }
}

extern "C" void kernel_launch(void* const* d_in, const int* in_sizes, int n_in,
                              void* d_out, int out_size, void* d_ws, size_t ws_size,
                              hipStream_t stream)
{
  (void)in_sizes; (void)n_in; (void)out_size; (void)ws_size;
  const float* xq   = (const float*)d_in[0];
  const float* xk   = (const float*)d_in[1];
  const float* xv   = (const float*)d_in[2];
  const float* mask = (const float*)d_in[3];
  const float* wq   = (const float*)d_in[4];
  const float* wk   = (const float*)d_in[5];
  const float* wv   = (const float*)d_in[6];
  const float* wo   = (const float*)d_in[7];
  const float* bo   = (const float*)d_in[8];
  float* out = (float*)d_out;

  char* ws = (char*)d_ws;                    // needs 56 MB
  short* Wall = (short*)(ws + (size_t)0);    // Wq/Wk/Wv contiguous
  short* Wot  = (short*)(ws + ((size_t)6 << 20));
  short* Xb   = (short*)(ws + ((size_t)8 << 20));   // 24 MB, dead after proj
  short* AO   = (short*)(ws + ((size_t)8 << 20));   // aliases Xq slot (8 MB)
  short* Qb   = (short*)(ws + ((size_t)32 << 20));
  short* Kt2  = (short*)(ws + ((size_t)40 << 20));  // K A-frag pre-tiled
  short* Vt2  = (short*)(ws + ((size_t)48 << 20));  // V^T pre-tiled, key-permuted

  prep_all<<<7168, 256, 0, stream>>>(xq, xk, xv, wq, wk, wv, wo, Xb, Wall, Wot);
  proj_qkv2<<<dim3(32, 8, 3), 256, 0, stream>>>(Xb, Wall, Qb, Kt2, Vt2);
  attn14<<<dim3(32, 16), 256, 0, stream>>>(Qb, Kt2, Vt2, mask, AO);
  out_proj2<<<dim3(32, 8), 256, 0, stream>>>(AO, Wot, bo, out);
}